// Round 4
// baseline (466.526 us; speedup 1.0000x reference)
//
#include <hip/hip_runtime.h>

// PetaloMixer: LN -> 4x shared-weight Mamba over parts -> skip -> LN -> proj
// B=2, C=256, L=4096, P=4, DM=64, DI=128, DS=16, DTR=4, OUT=256. fp32.
// GEMM pattern: row-per-thread, accumulators in VGPRs, weights via uniform
// (blockIdx/loop-derived) addresses -> compiler emits s_load (SMEM pipe).
// Scan: chunked, NCH=128 chunks of CHL=32, thread-owns-d (16 s-states).

#define B_    2
#define C_    256
#define L_    4096
#define P_    4
#define DM_   64
#define DI_   128
#define OUT_  256
#define NCH   128
#define CHL   32

// ---------------- K1: LayerNorm over C for (b,l), x is (b,c,l) ----------------
__global__ __launch_bounds__(256) void k1_ln(const float* __restrict__ x,
        const float* __restrict__ g, const float* __restrict__ bb,
        float* __restrict__ xn) {
  __shared__ float tile[256 * 17];
  __shared__ float reds[16 * 17];
  __shared__ float redq[16 * 17];
  __shared__ float smu[16], srs[16];
  int t = threadIdx.x;
  int l0 = blockIdx.x * 16;
  int b = blockIdx.y;
  // load: thread owns channel row c=t, 16 l values (4 x float4)
  const float* xb = x + ((size_t)b * C_ + t) * L_ + l0;
  #pragma unroll
  for (int i = 0; i < 4; ++i) {
    float4 u = *(const float4*)&xb[i * 4];
    tile[t * 17 + i * 4 + 0] = u.x;
    tile[t * 17 + i * 4 + 1] = u.y;
    tile[t * 17 + i * 4 + 2] = u.z;
    tile[t * 17 + i * 4 + 3] = u.w;
  }
  __syncthreads();
  {
    int l = t & 15, kg = t >> 4;   // kg: 16 groups of 16 channels
    float s = 0.f, q = 0.f;
    #pragma unroll
    for (int j = 0; j < 16; ++j) {
      float v = tile[(kg * 16 + j) * 17 + l];
      s += v; q += v * v;
    }
    reds[kg * 17 + l] = s;
    redq[kg * 17 + l] = q;
  }
  __syncthreads();
  if (t < 16) {
    float s = 0.f, q = 0.f;
    #pragma unroll
    for (int kg = 0; kg < 16; ++kg) { s += reds[kg * 17 + t]; q += redq[kg * 17 + t]; }
    float mu = s * (1.f / 256.f);
    smu[t] = mu;
    srs[t] = rsqrtf(q * (1.f / 256.f) - mu * mu + 1e-5f);
  }
  __syncthreads();
  float gc = g[t], bc = bb[t];
  #pragma unroll
  for (int l = 0; l < 16; ++l) {
    float v = (tile[t * 17 + l] - smu[l]) * srs[l] * gc + bc;
    xn[((size_t)b * L_ + l0 + l) * C_ + t] = v;
  }
}

// ---------------- K2: xz[row,0:256] = xn_part[row,64] @ W(256x64)^T ----------
// row-per-thread; 64 accumulators; weights via uniform s_load.
__global__ __launch_bounds__(64) void k2_inproj(const float* __restrict__ xn,
        const float* __restrict__ w, float* __restrict__ xz) {
  int t = threadIdx.x;
  int row = blockIdx.x * 64 + t;           // bp*L + l, 32768 rows
  int o0 = blockIdx.y * 64;
  int bp = row >> 12, l = row & 4095, b = bp >> 2, p = bp & 3;
  const float* xr = xn + ((size_t)b * L_ + l) * 256 + p * 64;
  float acc[64];
  #pragma unroll
  for (int oo = 0; oo < 64; ++oo) acc[oo] = 0.f;
  #pragma unroll 2
  for (int k4 = 0; k4 < 16; ++k4) {
    float4 a4 = *(const float4*)&xr[k4 * 4];
    const float* wp = w + (size_t)o0 * 64 + k4 * 4;   // uniform
    #pragma unroll
    for (int oo = 0; oo < 64; ++oo) {
      float4 w4 = *(const float4*)&wp[(size_t)oo * 64];
      acc[oo] += a4.x * w4.x + a4.y * w4.y + a4.z * w4.z + a4.w * w4.w;
    }
  }
  float* orow = xz + (size_t)row * 256 + o0;
  #pragma unroll
  for (int q = 0; q < 16; ++q) {
    float4 v = make_float4(acc[q * 4 + 0], acc[q * 4 + 1], acc[q * 4 + 2], acc[q * 4 + 3]);
    *(float4*)&orow[q * 4] = v;
  }
}

// ---------------- K3a: causal depthwise conv(4) + silu -----------------------
__global__ __launch_bounds__(256) void k3a_conv(const float* __restrict__ xz,
        const float* __restrict__ conv_w, const float* __restrict__ conv_b,
        float* __restrict__ xc) {
  int t = threadIdx.x;
  int d = t & 127, lh = t >> 7;
  int bp = blockIdx.y;
  int lstart = blockIdx.x * 32 + lh * 16;
  const float* xzb = xz + (size_t)bp * L_ * 256;
  float4 cw = *(const float4*)&conv_w[d * 4];
  float cb = conv_b[d];
  float w0 = (lstart >= 3) ? xzb[(size_t)(lstart - 3) * 256 + d] : 0.f;
  float w1 = (lstart >= 2) ? xzb[(size_t)(lstart - 2) * 256 + d] : 0.f;
  float w2 = (lstart >= 1) ? xzb[(size_t)(lstart - 1) * 256 + d] : 0.f;
  const float* xzrow = xzb + (size_t)lstart * 256 + d;
  float* xcrow = xc + ((size_t)bp * L_ + lstart) * 128 + d;
  #pragma unroll 4
  for (int i = 0; i < 16; ++i) {
    float w3 = xzrow[(size_t)i * 256];
    float cv = cb + cw.x * w0 + cw.y * w1 + cw.z * w2 + cw.w * w3;
    float sv = __fdividef(cv, 1.f + __expf(-cv));
    xcrow[(size_t)i * 128] = sv;
    w0 = w1; w1 = w2; w2 = w3;
  }
}

// ---------------- K3b: x_dbl = xc @ x_proj_w^T (+ fused dt softplus) ---------
// row-per-thread; 18 ra per thread (half of 36); rh==0 also computes dt.
__global__ __launch_bounds__(64) void k3b_xdbl(const float* __restrict__ xc,
        const float* __restrict__ x_proj_w, const float* __restrict__ dt_proj_w,
        const float* __restrict__ dt_proj_b,
        float* __restrict__ bc, float* __restrict__ dt) {
  int t = threadIdx.x;
  int row = blockIdx.x * 64 + t;           // bp*L + l, 32768 rows
  int rh = blockIdx.y;                     // 0: ra 0..17, 1: ra 18..35
  const float* ar = xc + (size_t)row * 128;
  float acc[18];
  #pragma unroll
  for (int rr = 0; rr < 18; ++rr) acc[rr] = 0.f;
  #pragma unroll 2
  for (int k4 = 0; k4 < 32; ++k4) {
    float4 a4 = *(const float4*)&ar[k4 * 4];
    const float* wp = x_proj_w + rh * 18 * 128 + k4 * 4;   // uniform
    #pragma unroll
    for (int rr = 0; rr < 18; ++rr) {
      float4 w4 = *(const float4*)&wp[rr * 128];
      acc[rr] += a4.x * w4.x + a4.y * w4.y + a4.z * w4.z + a4.w * w4.w;
    }
  }
  if (rh == 0) {
    // acc[0..3] = dt partials, acc[4..17] -> bc[0..13]
    #pragma unroll
    for (int rr = 4; rr < 18; ++rr) bc[(size_t)row * 32 + (rr - 4)] = acc[rr];
    float* dtr = dt + (size_t)row * 128;
    #pragma unroll 2
    for (int d4 = 0; d4 < 32; ++d4) {
      float4 o;
      #pragma unroll
      for (int j = 0; j < 4; ++j) {
        int dd = d4 * 4 + j;
        float4 w4 = *(const float4*)&dt_proj_w[dd * 4];    // uniform
        float v = dt_proj_b[dd] + acc[0] * w4.x + acc[1] * w4.y
                                + acc[2] * w4.z + acc[3] * w4.w;
        float sp = (v > 20.f) ? v : __logf(1.f + __expf(v));
        (&o.x)[j] = sp;
      }
      *(float4*)&dtr[d4 * 4] = o;
    }
  } else {
    #pragma unroll
    for (int rr = 0; rr < 18; ++rr) bc[(size_t)row * 32 + 14 + rr] = acc[rr];
  }
}

// ---------------- K4a: per-chunk (aprod, h_end | h0=0), thread owns d --------
__global__ __launch_bounds__(128) void k4a_scanA(const float* __restrict__ dt,
        const float* __restrict__ xc, const float* __restrict__ bcbuf,
        const float* __restrict__ A_log,
        float* __restrict__ chA, float* __restrict__ chH) {
  int d = threadIdx.x;
  int ch = blockIdx.x, bp = blockIdx.y;
  float Av[16], h[16];
  #pragma unroll
  for (int q = 0; q < 4; ++q) {
    float4 a = *(const float4*)&A_log[d * 16 + q * 4];
    Av[q*4+0] = -__expf(a.x); Av[q*4+1] = -__expf(a.y);
    Av[q*4+2] = -__expf(a.z); Av[q*4+3] = -__expf(a.w);
  }
  #pragma unroll
  for (int s = 0; s < 16; ++s) h[s] = 0.f;
  float sumdt = 0.f;
  const float* dtp = dt + (size_t)bp * L_ * 128 + (size_t)ch * CHL * 128 + d;
  const float* xcp = xc + (size_t)bp * L_ * 128 + (size_t)ch * CHL * 128 + d;
  const float* bcp = bcbuf + (size_t)bp * L_ * 32 + (size_t)ch * CHL * 32;
  #pragma unroll 2
  for (int tt = 0; tt < CHL; ++tt) {
    float dtv = dtp[tt * 128];
    float xcv = xcp[tt * 128];
    float Bv[16];
    *(float4*)&Bv[0]  = *(const float4*)&bcp[tt * 32 + 0];
    *(float4*)&Bv[4]  = *(const float4*)&bcp[tt * 32 + 4];
    *(float4*)&Bv[8]  = *(const float4*)&bcp[tt * 32 + 8];
    *(float4*)&Bv[12] = *(const float4*)&bcp[tt * 32 + 12];
    float w = dtv * xcv;
    sumdt += dtv;
    #pragma unroll
    for (int s = 0; s < 16; ++s) {
      float dA = __expf(dtv * Av[s]);
      h[s] = fmaf(dA, h[s], w * Bv[s]);
    }
  }
  size_t o = (((size_t)bp * NCH + ch) * 128 + d) * 16;
  #pragma unroll
  for (int s = 0; s < 16; ++s) chA[o + s] = __expf(sumdt * Av[s]);
  #pragma unroll
  for (int s = 0; s < 16; ++s) chH[o + s] = h[s];
}

// ---------------- K4b: exclusive scan over chunk states (in-place into chH) --
__global__ __launch_bounds__(256) void k4b_fold(const float* __restrict__ chA,
        float* __restrict__ chH) {
  int tid = blockIdx.x * 256 + threadIdx.x;   // 16384 threads
  int bp = tid >> 11;
  int rem = tid & 2047;
  float h = 0.f;
  for (int ch = 0; ch < NCH; ++ch) {
    size_t o = ((size_t)bp * NCH + ch) * 2048 + rem;
    float a = chA[o];
    float e = chH[o];
    chH[o] = h;            // exclusive prefix
    h = fmaf(a, h, e);
  }
}

// ---------------- K5: outputs — recurrence from h0, y, D-skip, silu(z) gate --
__global__ __launch_bounds__(128) void k5_scanB(const float* __restrict__ dt,
        const float* __restrict__ xc, const float* __restrict__ bcbuf,
        const float* __restrict__ xz, const float* __restrict__ A_log,
        const float* __restrict__ D_param, const float* __restrict__ chH,
        float* __restrict__ yg) {
  int d = threadIdx.x;
  int ch = blockIdx.x, bp = blockIdx.y;
  float Av[16], h[16];
  #pragma unroll
  for (int q = 0; q < 4; ++q) {
    float4 a = *(const float4*)&A_log[d * 16 + q * 4];
    Av[q*4+0] = -__expf(a.x); Av[q*4+1] = -__expf(a.y);
    Av[q*4+2] = -__expf(a.z); Av[q*4+3] = -__expf(a.w);
  }
  {
    size_t o = (((size_t)bp * NCH + ch) * 128 + d) * 16;
    #pragma unroll
    for (int q = 0; q < 4; ++q)
      *(float4*)&h[q * 4] = *(const float4*)&chH[o + q * 4];
  }
  float Dv = D_param[d];
  const float* dtp = dt + (size_t)bp * L_ * 128 + (size_t)ch * CHL * 128 + d;
  const float* xcp = xc + (size_t)bp * L_ * 128 + (size_t)ch * CHL * 128 + d;
  const float* bcp = bcbuf + (size_t)bp * L_ * 32 + (size_t)ch * CHL * 32;
  const float* zp  = xz + (size_t)bp * L_ * 256 + (size_t)ch * CHL * 256 + 128 + d;
  float* ygp = yg + (size_t)bp * L_ * 128 + (size_t)ch * CHL * 128 + d;
  #pragma unroll 2
  for (int tt = 0; tt < CHL; ++tt) {
    float dtv = dtp[tt * 128];
    float xcv = xcp[tt * 128];
    float zv  = zp[tt * 256];
    float Bv[16], Cv[16];
    *(float4*)&Bv[0]  = *(const float4*)&bcp[tt * 32 + 0];
    *(float4*)&Bv[4]  = *(const float4*)&bcp[tt * 32 + 4];
    *(float4*)&Bv[8]  = *(const float4*)&bcp[tt * 32 + 8];
    *(float4*)&Bv[12] = *(const float4*)&bcp[tt * 32 + 12];
    *(float4*)&Cv[0]  = *(const float4*)&bcp[tt * 32 + 16];
    *(float4*)&Cv[4]  = *(const float4*)&bcp[tt * 32 + 20];
    *(float4*)&Cv[8]  = *(const float4*)&bcp[tt * 32 + 24];
    *(float4*)&Cv[12] = *(const float4*)&bcp[tt * 32 + 28];
    float w = dtv * xcv;
    float r = 0.f;
    #pragma unroll
    for (int s = 0; s < 16; ++s) {
      float dA = __expf(dtv * Av[s]);
      h[s] = fmaf(dA, h[s], w * Bv[s]);
      r = fmaf(h[s], Cv[s], r);
    }
    float y = fmaf(Dv, xcv, r);
    float sig = __fdividef(1.f, 1.f + __expf(-zv));
    ygp[tt * 128] = y * (zv * sig);
  }
}

// ---------------- K6a: out_proj + skip (row-per-thread, scalar weights) ------
__global__ __launch_bounds__(64) void k6a_gemm(const float* __restrict__ yg,
        const float* __restrict__ xn, const float* __restrict__ opw,
        const float* __restrict__ skip, float* __restrict__ xmn) {
  int t = threadIdx.x;
  int row = blockIdx.x * 64 + t;           // bp*L + l, 32768 rows
  int oh = blockIdx.y;                     // o0 = oh*32
  int bp = row >> 12, l = row & 4095, b = bp >> 2, p = bp & 3;
  const float* ar = yg + (size_t)row * 128;
  float acc[32];
  #pragma unroll
  for (int rr = 0; rr < 32; ++rr) acc[rr] = 0.f;
  #pragma unroll 2
  for (int k4 = 0; k4 < 32; ++k4) {
    float4 a4 = *(const float4*)&ar[k4 * 4];
    const float* wp = opw + (size_t)(oh * 32) * 128 + k4 * 4;   // uniform
    #pragma unroll
    for (int rr = 0; rr < 32; ++rr) {
      float4 w4 = *(const float4*)&wp[rr * 128];
      acc[rr] += a4.x * w4.x + a4.y * w4.y + a4.z * w4.z + a4.w * w4.w;
    }
  }
  float sk = skip[0];
  size_t base = ((size_t)b * L_ + l) * 256 + p * 64 + oh * 32;
  #pragma unroll
  for (int q = 0; q < 8; ++q) {
    float4 xv = *(const float4*)&xn[base + q * 4];
    float4 v = make_float4(acc[q*4+0] + sk * xv.x, acc[q*4+1] + sk * xv.y,
                           acc[q*4+2] + sk * xv.z, acc[q*4+3] + sk * xv.w);
    *(float4*)&xmn[base + q * 4] = v;
  }
}

// ---------------- K6ln: row LayerNorm over C (rows contiguous), in-place -----
__global__ __launch_bounds__(256) void k6ln(float* __restrict__ xmn,
        const float* __restrict__ g, const float* __restrict__ bb) {
  int t = threadIdx.x;
  int row = blockIdx.x * 4 + (t >> 6);
  int lane = t & 63;
  float* rp = xmn + (size_t)row * 256 + lane * 4;
  float4 v = *(const float4*)rp;
  float s = v.x + v.y + v.z + v.w;
  float q = v.x * v.x + v.y * v.y + v.z * v.z + v.w * v.w;
  #pragma unroll
  for (int off = 1; off < 64; off <<= 1) {
    s += __shfl_xor(s, off);
    q += __shfl_xor(q, off);
  }
  float mu = s * (1.f / 256.f);
  float rs = rsqrtf(q * (1.f / 256.f) - mu * mu + 1e-5f);
  float4 g4 = *(const float4*)&g[lane * 4];
  float4 b4 = *(const float4*)&bb[lane * 4];
  float4 o = make_float4((v.x - mu) * rs * g4.x + b4.x,
                         (v.y - mu) * rs * g4.y + b4.y,
                         (v.z - mu) * rs * g4.z + b4.z,
                         (v.w - mu) * rs * g4.w + b4.w);
  *(float4*)rp = o;
}

// ---------------- K6b: out[b,o,l] = xmn[row,:] @ proj_w[o,:] + pb[o] ---------
__global__ __launch_bounds__(64) void k6b_proj(const float* __restrict__ xmn,
        const float* __restrict__ pw, const float* __restrict__ pb,
        float* __restrict__ out) {
  int t = threadIdx.x;
  int row = blockIdx.x * 64 + t;           // b*L + l, 8192 rows
  int o0 = blockIdx.y * 32;
  int b = row >> 12, l = row & 4095;
  const float* ar = xmn + (size_t)row * 256;
  float acc[32];
  #pragma unroll
  for (int oo = 0; oo < 32; ++oo) acc[oo] = 0.f;
  #pragma unroll 2
  for (int k4 = 0; k4 < 64; ++k4) {
    float4 a4 = *(const float4*)&ar[k4 * 4];
    const float* wp = pw + (size_t)o0 * 256 + k4 * 4;   // uniform
    #pragma unroll
    for (int oo = 0; oo < 32; ++oo) {
      float4 w4 = *(const float4*)&wp[(size_t)oo * 256];
      acc[oo] += a4.x * w4.x + a4.y * w4.y + a4.z * w4.z + a4.w * w4.w;
    }
  }
  #pragma unroll
  for (int oo = 0; oo < 32; ++oo) {
    out[((size_t)b * OUT_ + o0 + oo) * L_ + l] = acc[oo] + pb[o0 + oo];
  }
}

extern "C" void kernel_launch(void* const* d_in, const int* in_sizes, int n_in,
                              void* d_out, int out_size, void* d_ws, size_t ws_size,
                              hipStream_t stream) {
  (void)in_sizes; (void)n_in; (void)out_size; (void)ws_size;
  const float* x          = (const float*)d_in[0];
  const float* ln_g       = (const float*)d_in[1];
  const float* ln_b       = (const float*)d_in[2];
  const float* in_proj_w  = (const float*)d_in[3];
  const float* conv_w     = (const float*)d_in[4];
  const float* conv_b     = (const float*)d_in[5];
  const float* x_proj_w   = (const float*)d_in[6];
  const float* dt_proj_w  = (const float*)d_in[7];
  const float* dt_proj_b  = (const float*)d_in[8];
  const float* A_log      = (const float*)d_in[9];
  const float* D_param    = (const float*)d_in[10];
  const float* out_proj_w = (const float*)d_in[11];
  const float* proj_w     = (const float*)d_in[12];
  const float* proj_b     = (const float*)d_in[13];
  const float* skip_scale = (const float*)d_in[14];

  float* ws  = (float*)d_ws;
  float* xn  = ws;              // 2,097,152 f
  float* xz  = xn + 2097152;    // 8,388,608 f
  float* xc  = xz + 8388608;    // 4,194,304 f
  float* dt  = xc + 4194304;    // 4,194,304 f
  float* bc  = dt + 4194304;    // 1,048,576 f
  float* chA = bc + 1048576;    // 2,097,152 f
  float* chH = chA + 2097152;   // 2,097,152 f  (k4b folds h0 in-place here)
  float* yg  = chH + 2097152;   // 4,194,304 f
  float* xmn = yg + 4194304;    // 2,097,152 f
  float* out = (float*)d_out;

  k1_ln<<<dim3(L_ / 16, B_), 256, 0, stream>>>(x, ln_g, ln_b, xn);
  k2_inproj<<<dim3(512, 4), 64, 0, stream>>>(xn, in_proj_w, xz);
  k3a_conv<<<dim3(128, B_ * P_), 256, 0, stream>>>(xz, conv_w, conv_b, xc);
  k3b_xdbl<<<dim3(512, 2), 64, 0, stream>>>(xc, x_proj_w, dt_proj_w,
      dt_proj_b, bc, dt);
  k4a_scanA<<<dim3(NCH, B_ * P_), 128, 0, stream>>>(dt, xc, bc, A_log, chA, chH);
  k4b_fold<<<dim3(64), 256, 0, stream>>>(chA, chH);
  k5_scanB<<<dim3(NCH, B_ * P_), 128, 0, stream>>>(dt, xc, bc, xz, A_log,
      D_param, chH, yg);
  k6a_gemm<<<dim3(512, 2), 64, 0, stream>>>(yg, xn, out_proj_w,
      skip_scale, xmn);
  k6ln<<<dim3(B_ * L_ / 4), 256, 0, stream>>>(xmn, ln_g, ln_b);
  k6b_proj<<<dim3(128, 8), 64, 0, stream>>>(xmn, proj_w, proj_b, out);
}

// Round 5
// 254.410 us; speedup vs baseline: 1.8338x; 1.8338x over previous
//
#include <hip/hip_runtime.h>

// PetaloMixer: LN -> 4x shared-weight Mamba over parts -> skip -> LN -> proj
// B=2, C=256, L=4096, P=4, DM=64, DI=128, DS=16, DTR=4, OUT=256. fp32.
// GEMM template: 64-row LDS-staged activations (coalesced), weights via
// wave-uniform (readfirstlane) addresses -> s_load, 16 accs/thread.
// Scan: chunked, NCH=128 chunks of CHL=32, thread-owns-d; 3-level chunk fold.

#define B_    2
#define C_    256
#define L_    4096
#define P_    4
#define DM_   64
#define DI_   128
#define OUT_  256
#define NCH   128
#define CHL   32

// ---------------- K1: LayerNorm over C for (b,l), x is (b,c,l) ----------------
__global__ __launch_bounds__(256) void k1_ln(const float* __restrict__ x,
        const float* __restrict__ g, const float* __restrict__ bb,
        float* __restrict__ xn) {
  __shared__ float tile[256][33];
  __shared__ float psum[8][32];
  __shared__ float psq[8][32];
  __shared__ float smu[32], srs[32];
  int t = threadIdx.x;
  int l0 = blockIdx.x * 32;
  int b = blockIdx.y;
  const float* xb = x + (size_t)b * C_ * L_;
  int ll = t & 31, cr = t >> 5;
  for (int i = 0; i < 32; ++i) {
    int c = cr + 8 * i;
    tile[c][ll] = xb[(size_t)c * L_ + l0 + ll];
  }
  __syncthreads();
  {
    int l = t & 31, k = t >> 5;
    float s = 0.f, sq = 0.f;
    #pragma unroll 8
    for (int j = 0; j < 32; ++j) {
      float v = tile[32 * k + j][l];
      s += v; sq += v * v;
    }
    psum[k][l] = s; psq[k][l] = sq;
  }
  __syncthreads();
  if (t < 32) {
    float s = 0.f, sq = 0.f;
    #pragma unroll
    for (int k = 0; k < 8; ++k) { s += psum[k][t]; sq += psq[k][t]; }
    float mu = s * (1.f / 256.f);
    float var = sq * (1.f / 256.f) - mu * mu;
    smu[t] = mu;
    srs[t] = rsqrtf(var + 1e-5f);
  }
  __syncthreads();
  float gc = g[t], bc = bb[t];
  for (int l = 0; l < 32; ++l) {
    float v = (tile[t][l] - smu[l]) * srs[l] * gc + bc;
    xn[((size_t)b * L_ + l0 + l) * C_ + t] = v;
  }
}

// ---------------- K2 v3: xz[row, o0:o0+64] = xn_part[row,64] @ W^T -----------
// grid (512 row-blocks, 4 o-quarters), 256 thr. acts LDS, weights s_load.
__global__ __launch_bounds__(256) void k2_inproj(const float* __restrict__ xn,
        const float* __restrict__ w, float* __restrict__ xz) {
  __shared__ float sa[64 * 68];
  __shared__ float sxz[64 * 68];
  int t = threadIdx.x;
  int row0 = blockIdx.x * 64;
  int o0 = blockIdx.y * 64;
  int bp = row0 >> 12, b = bp >> 2, p = bp & 3, l0 = row0 & 4095;
  // stage acts: 64 rows x 16 quads
  #pragma unroll
  for (int i = 0; i < 4; ++i) {
    int idx = t + 256 * i;
    int row = idx >> 4, kq = idx & 15;
    float4 v = *(const float4*)&xn[((size_t)b * L_ + l0 + row) * 256 + p * 64 + kq * 4];
    *(float4*)&sa[row * 68 + kq * 4] = v;
  }
  __syncthreads();
  int l = t & 63;
  int ogu = __builtin_amdgcn_readfirstlane(t >> 6);
  int ob = o0 + ogu * 16;
  float acc[16];
  #pragma unroll
  for (int c = 0; c < 16; ++c) acc[c] = 0.f;
  for (int k4 = 0; k4 < 16; ++k4) {
    float4 a4 = *(const float4*)&sa[l * 68 + k4 * 4];
    const float* wp = w + (size_t)ob * 64 + k4 * 4;
    #pragma unroll
    for (int c = 0; c < 16; ++c) {
      float4 w4 = *(const float4*)&wp[c * 64];
      acc[c] += a4.x * w4.x + a4.y * w4.y + a4.z * w4.z + a4.w * w4.w;
    }
  }
  // transpose through LDS for coalesced row-major writes
  int ogl = t >> 6;
  #pragma unroll
  for (int c4 = 0; c4 < 4; ++c4) {
    float4 v = make_float4(acc[c4*4+0], acc[c4*4+1], acc[c4*4+2], acc[c4*4+3]);
    *(float4*)&sxz[l * 68 + ogl * 16 + c4 * 4] = v;
  }
  __syncthreads();
  #pragma unroll
  for (int i = 0; i < 4; ++i) {
    int idx = t + 256 * i;
    int row = idx >> 4, cq = idx & 15;
    float4 v = *(const float4*)&sxz[row * 68 + cq * 4];
    *(float4*)&xz[(size_t)(row0 + row) * 256 + o0 + cq * 4] = v;
  }
}

// ---------------- K3a: causal depthwise conv(4) + silu (streaming) -----------
__global__ __launch_bounds__(256) void k3a_conv(const float* __restrict__ xz,
        const float* __restrict__ conv_w, const float* __restrict__ conv_b,
        float* __restrict__ xc) {
  int t = threadIdx.x;
  int d = t & 127, lh = t >> 7;
  int bp = blockIdx.y;
  int lstart = blockIdx.x * 32 + lh * 16;
  const float* xzb = xz + (size_t)bp * L_ * 256;
  float4 cw = *(const float4*)&conv_w[d * 4];
  float cb = conv_b[d];
  float w0 = (lstart >= 3) ? xzb[(size_t)(lstart - 3) * 256 + d] : 0.f;
  float w1 = (lstart >= 2) ? xzb[(size_t)(lstart - 2) * 256 + d] : 0.f;
  float w2 = (lstart >= 1) ? xzb[(size_t)(lstart - 1) * 256 + d] : 0.f;
  const float* xzrow = xzb + (size_t)lstart * 256 + d;
  float* xcrow = xc + ((size_t)bp * L_ + lstart) * 128 + d;
  #pragma unroll 4
  for (int i = 0; i < 16; ++i) {
    float w3 = xzrow[(size_t)i * 256];
    float cv = cb + cw.x * w0 + cw.y * w1 + cw.z * w2 + cw.w * w3;
    float sv = __fdividef(cv, 1.f + __expf(-cv));
    xcrow[(size_t)i * 128] = sv;
    w0 = w1; w1 = w2; w2 = w3;
  }
}

// ---------------- K3b v3: x_dbl = xc @ x_proj_w^T, fused dt ------------------
// grid (512 row-blocks), 256 thr = 64 l x 4 og (9 cols each, 36 total).
__global__ __launch_bounds__(256) void k3b_xdbl(const float* __restrict__ xc,
        const float* __restrict__ x_proj_w, const float* __restrict__ dt_proj_w,
        const float* __restrict__ dt_proj_b,
        float* __restrict__ bc, float* __restrict__ dt) {
  __shared__ float sa[64 * 132];
  __shared__ float sbc[64 * 33];
  __shared__ float sdb[64 * 8];
  int t = threadIdx.x;
  int row0 = blockIdx.x * 64;
  // stage acts: 64 rows x 32 quads
  #pragma unroll
  for (int i = 0; i < 8; ++i) {
    int idx = t + 256 * i;
    int row = idx >> 5, kq = idx & 31;
    float4 v = *(const float4*)&xc[(size_t)(row0 + row) * 128 + kq * 4];
    *(float4*)&sa[row * 132 + kq * 4] = v;
  }
  __syncthreads();
  int l = t & 63;
  int ogu = __builtin_amdgcn_readfirstlane(t >> 6);
  float acc[9];
  #pragma unroll
  for (int rr = 0; rr < 9; ++rr) acc[rr] = 0.f;
  for (int k4 = 0; k4 < 32; ++k4) {
    float4 a4 = *(const float4*)&sa[l * 132 + k4 * 4];
    const float* wp = x_proj_w + (size_t)(ogu * 9) * 128 + k4 * 4;
    #pragma unroll
    for (int rr = 0; rr < 9; ++rr) {
      float4 w4 = *(const float4*)&wp[rr * 128];
      acc[rr] += a4.x * w4.x + a4.y * w4.y + a4.z * w4.z + a4.w * w4.w;
    }
  }
  if (ogu == 0) {
    #pragma unroll
    for (int rr = 0; rr < 4; ++rr) sdb[l * 8 + rr] = acc[rr];
    #pragma unroll
    for (int rr = 4; rr < 9; ++rr) sbc[l * 33 + (rr - 4)] = acc[rr];
  } else {
    #pragma unroll
    for (int rr = 0; rr < 9; ++rr) sbc[l * 33 + (ogu * 9 + rr - 4)] = acc[rr];
  }
  __syncthreads();
  // coalesced bc writeout
  #pragma unroll
  for (int i = 0; i < 8; ++i) {
    int idx = t + 256 * i;
    int row = idx >> 5, col = idx & 31;
    bc[(size_t)(row0 + row) * 32 + col] = sbc[row * 33 + col];
  }
  // dt = softplus(partials @ dt_proj_w^T + b)
  {
    int d = t & 127, rh = t >> 7;
    float4 dw = *(const float4*)&dt_proj_w[d * 4];
    float dpb = dt_proj_b[d];
    #pragma unroll 4
    for (int i = 0; i < 32; ++i) {
      int row = rh * 32 + i;
      float4 q = *(const float4*)&sdb[row * 8];
      float v = dpb + q.x * dw.x + q.y * dw.y + q.z * dw.z + q.w * dw.w;
      float sp = (v > 20.f) ? v : __logf(1.f + __expf(v));
      dt[(size_t)(row0 + row) * 128 + d] = sp;
    }
  }
}

// ---------------- K4a: per-chunk (aprod, h_end | h0=0), thread owns d --------
__global__ __launch_bounds__(128) void k4a_scanA(const float* __restrict__ dt,
        const float* __restrict__ xc, const float* __restrict__ bcbuf,
        const float* __restrict__ A_log,
        float* __restrict__ chA, float* __restrict__ chH) {
  int d = threadIdx.x;
  int ch = blockIdx.x, bp = blockIdx.y;
  float Av[16], h[16];
  #pragma unroll
  for (int q = 0; q < 4; ++q) {
    float4 a = *(const float4*)&A_log[d * 16 + q * 4];
    Av[q*4+0] = -__expf(a.x); Av[q*4+1] = -__expf(a.y);
    Av[q*4+2] = -__expf(a.z); Av[q*4+3] = -__expf(a.w);
  }
  #pragma unroll
  for (int s = 0; s < 16; ++s) h[s] = 0.f;
  float sumdt = 0.f;
  const float* dtp = dt + (size_t)bp * L_ * 128 + (size_t)ch * CHL * 128 + d;
  const float* xcp = xc + (size_t)bp * L_ * 128 + (size_t)ch * CHL * 128 + d;
  const float* bcp = bcbuf + (size_t)bp * L_ * 32 + (size_t)ch * CHL * 32;
  #pragma unroll 2
  for (int tt = 0; tt < CHL; ++tt) {
    float dtv = dtp[tt * 128];
    float xcv = xcp[tt * 128];
    float Bv[16];
    *(float4*)&Bv[0]  = *(const float4*)&bcp[tt * 32 + 0];
    *(float4*)&Bv[4]  = *(const float4*)&bcp[tt * 32 + 4];
    *(float4*)&Bv[8]  = *(const float4*)&bcp[tt * 32 + 8];
    *(float4*)&Bv[12] = *(const float4*)&bcp[tt * 32 + 12];
    float w = dtv * xcv;
    sumdt += dtv;
    #pragma unroll
    for (int s = 0; s < 16; ++s) {
      float dA = __expf(dtv * Av[s]);
      h[s] = fmaf(dA, h[s], w * Bv[s]);
    }
  }
  size_t o = (((size_t)bp * NCH + ch) * 128 + d) * 16;
  #pragma unroll
  for (int s = 0; s < 16; ++s) chA[o + s] = __expf(sumdt * Av[s]);
  #pragma unroll
  for (int s = 0; s < 16; ++s) chH[o + s] = h[s];
}

// ---------------- K4b: 3-level chunk-state fold (chain 128 -> 8/16/8) --------
__global__ __launch_bounds__(256) void k4b1(const float* __restrict__ chA,
        const float* __restrict__ chH, float* __restrict__ pA,
        float* __restrict__ pH) {
  int tid = blockIdx.x * 256 + threadIdx.x;   // 262144
  int rem = tid & 2047, g = (tid >> 11) & 15, bp = tid >> 15;
  float a = 1.f, h = 0.f;
  #pragma unroll 2
  for (int i = 0; i < 8; ++i) {
    size_t o = ((size_t)(bp * NCH + g * 8 + i)) * 2048 + rem;
    float ca = chA[o], ce = chH[o];
    h = fmaf(ca, h, ce);
    a *= ca;
  }
  pA[tid] = a; pH[tid] = h;
}

__global__ __launch_bounds__(256) void k4b2(const float* __restrict__ pA,
        const float* __restrict__ pH, float* __restrict__ gH) {
  int tid = blockIdx.x * 256 + threadIdx.x;   // 16384
  int rem = tid & 2047, bp = tid >> 11;
  float h = 0.f;
  for (int g = 0; g < 16; ++g) {
    int o = (bp << 15) + (g << 11) + rem;
    gH[o] = h;
    h = fmaf(pA[o], h, pH[o]);
  }
}

__global__ __launch_bounds__(256) void k4b3(const float* __restrict__ chA,
        float* __restrict__ chH, const float* __restrict__ gH) {
  int tid = blockIdx.x * 256 + threadIdx.x;   // 262144
  int rem = tid & 2047, g = (tid >> 11) & 15, bp = tid >> 15;
  float h = gH[tid];
  #pragma unroll 2
  for (int i = 0; i < 8; ++i) {
    size_t o = ((size_t)(bp * NCH + g * 8 + i)) * 2048 + rem;
    float a = chA[o], e = chH[o];
    chH[o] = h;           // exclusive prefix for k5
    h = fmaf(a, h, e);
  }
}

// ---------------- K5: outputs — recurrence from h0, y, D-skip, silu(z) gate --
__global__ __launch_bounds__(128) void k5_scanB(const float* __restrict__ dt,
        const float* __restrict__ xc, const float* __restrict__ bcbuf,
        const float* __restrict__ xz, const float* __restrict__ A_log,
        const float* __restrict__ D_param, const float* __restrict__ chH,
        float* __restrict__ yg) {
  int d = threadIdx.x;
  int ch = blockIdx.x, bp = blockIdx.y;
  float Av[16], h[16];
  #pragma unroll
  for (int q = 0; q < 4; ++q) {
    float4 a = *(const float4*)&A_log[d * 16 + q * 4];
    Av[q*4+0] = -__expf(a.x); Av[q*4+1] = -__expf(a.y);
    Av[q*4+2] = -__expf(a.z); Av[q*4+3] = -__expf(a.w);
  }
  {
    size_t o = (((size_t)bp * NCH + ch) * 128 + d) * 16;
    #pragma unroll
    for (int q = 0; q < 4; ++q)
      *(float4*)&h[q * 4] = *(const float4*)&chH[o + q * 4];
  }
  float Dv = D_param[d];
  const float* dtp = dt + (size_t)bp * L_ * 128 + (size_t)ch * CHL * 128 + d;
  const float* xcp = xc + (size_t)bp * L_ * 128 + (size_t)ch * CHL * 128 + d;
  const float* bcp = bcbuf + (size_t)bp * L_ * 32 + (size_t)ch * CHL * 32;
  const float* zp  = xz + (size_t)bp * L_ * 256 + (size_t)ch * CHL * 256 + 128 + d;
  float* ygp = yg + (size_t)bp * L_ * 128 + (size_t)ch * CHL * 128 + d;
  #pragma unroll 2
  for (int tt = 0; tt < CHL; ++tt) {
    float dtv = dtp[tt * 128];
    float xcv = xcp[tt * 128];
    float zv  = zp[tt * 256];
    float Bv[16], Cv[16];
    *(float4*)&Bv[0]  = *(const float4*)&bcp[tt * 32 + 0];
    *(float4*)&Bv[4]  = *(const float4*)&bcp[tt * 32 + 4];
    *(float4*)&Bv[8]  = *(const float4*)&bcp[tt * 32 + 8];
    *(float4*)&Bv[12] = *(const float4*)&bcp[tt * 32 + 12];
    *(float4*)&Cv[0]  = *(const float4*)&bcp[tt * 32 + 16];
    *(float4*)&Cv[4]  = *(const float4*)&bcp[tt * 32 + 20];
    *(float4*)&Cv[8]  = *(const float4*)&bcp[tt * 32 + 24];
    *(float4*)&Cv[12] = *(const float4*)&bcp[tt * 32 + 28];
    float w = dtv * xcv;
    float r = 0.f;
    #pragma unroll
    for (int s = 0; s < 16; ++s) {
      float dA = __expf(dtv * Av[s]);
      h[s] = fmaf(dA, h[s], w * Bv[s]);
      r = fmaf(h[s], Cv[s], r);
    }
    float y = fmaf(Dv, xcv, r);
    float sig = __fdividef(1.f, 1.f + __expf(-zv));
    ygp[tt * 128] = y * (zv * sig);
  }
}

// ---------------- K6a v3: out_proj + skip ------------------------------------
// grid (512 row-blocks), 256 thr = 64 l x 4 og (16 cols each, 64 total).
__global__ __launch_bounds__(256) void k6a_gemm(const float* __restrict__ yg,
        const float* __restrict__ xn, const float* __restrict__ opw,
        const float* __restrict__ skip, float* __restrict__ xmn) {
  __shared__ float sa[64 * 132];
  __shared__ float sxm[64 * 68];
  int t = threadIdx.x;
  int row0 = blockIdx.x * 64;
  int bp = row0 >> 12, b = bp >> 2, p = bp & 3, l0 = row0 & 4095;
  #pragma unroll
  for (int i = 0; i < 8; ++i) {
    int idx = t + 256 * i;
    int row = idx >> 5, kq = idx & 31;
    float4 v = *(const float4*)&yg[(size_t)(row0 + row) * 128 + kq * 4];
    *(float4*)&sa[row * 132 + kq * 4] = v;
  }
  __syncthreads();
  int l = t & 63;
  int ogu = __builtin_amdgcn_readfirstlane(t >> 6);
  int ob = ogu * 16;
  float acc[16];
  #pragma unroll
  for (int c = 0; c < 16; ++c) acc[c] = 0.f;
  for (int k4 = 0; k4 < 32; ++k4) {
    float4 a4 = *(const float4*)&sa[l * 132 + k4 * 4];
    const float* wp = opw + (size_t)ob * 128 + k4 * 4;
    #pragma unroll
    for (int c = 0; c < 16; ++c) {
      float4 w4 = *(const float4*)&wp[c * 128];
      acc[c] += a4.x * w4.x + a4.y * w4.y + a4.z * w4.z + a4.w * w4.w;
    }
  }
  int ogl = t >> 6;
  #pragma unroll
  for (int c4 = 0; c4 < 4; ++c4) {
    float4 v = make_float4(acc[c4*4+0], acc[c4*4+1], acc[c4*4+2], acc[c4*4+3]);
    *(float4*)&sxm[l * 68 + ogl * 16 + c4 * 4] = v;
  }
  __syncthreads();
  float sk = skip[0];
  #pragma unroll
  for (int i = 0; i < 4; ++i) {
    int idx = t + 256 * i;
    int row = idx >> 4, cq = idx & 15;
    size_t addr = ((size_t)b * L_ + l0 + row) * 256 + p * 64 + cq * 4;
    float4 v = *(const float4*)&sxm[row * 68 + cq * 4];
    float4 xv = *(const float4*)&xn[addr];
    float4 o = make_float4(v.x + sk * xv.x, v.y + sk * xv.y,
                           v.z + sk * xv.z, v.w + sk * xv.w);
    *(float4*)&xmn[addr] = o;
  }
}

// ---------------- K6ln: row LayerNorm over C (rows contiguous), in-place -----
__global__ __launch_bounds__(256) void k6ln(float* __restrict__ xmn,
        const float* __restrict__ g, const float* __restrict__ bb) {
  int t = threadIdx.x;
  int row = blockIdx.x * 4 + (t >> 6);
  int lane = t & 63;
  float* rp = xmn + (size_t)row * 256 + lane * 4;
  float4 v = *(const float4*)rp;
  float s = v.x + v.y + v.z + v.w;
  float q = v.x * v.x + v.y * v.y + v.z * v.z + v.w * v.w;
  #pragma unroll
  for (int off = 1; off < 64; off <<= 1) {
    s += __shfl_xor(s, off);
    q += __shfl_xor(q, off);
  }
  float mu = s * (1.f / 256.f);
  float rs = rsqrtf(q * (1.f / 256.f) - mu * mu + 1e-5f);
  float4 g4 = *(const float4*)&g[lane * 4];
  float4 b4 = *(const float4*)&bb[lane * 4];
  float4 o = make_float4((v.x - mu) * rs * g4.x + b4.x,
                         (v.y - mu) * rs * g4.y + b4.y,
                         (v.z - mu) * rs * g4.z + b4.z,
                         (v.w - mu) * rs * g4.w + b4.w);
  *(float4*)rp = o;
}

// ---------------- K6b v3: out[b,o,l] = xmn[row,:] @ proj_w[o,:] + pb[o] ------
// grid (128 row-blocks, 4 o-quarters), 256 thr = 64 l x 4 og (16 cols each).
__global__ __launch_bounds__(256) void k6b_proj(const float* __restrict__ xmn,
        const float* __restrict__ pw, const float* __restrict__ pb,
        float* __restrict__ out) {
  __shared__ float sa[64 * 132];
  int t = threadIdx.x;
  int row0 = blockIdx.x * 64;
  int o0 = blockIdx.y * 64;
  int b = row0 >> 12, l0 = row0 & 4095;
  int l = t & 63;
  int ogu = __builtin_amdgcn_readfirstlane(t >> 6);
  int ob = o0 + ogu * 16;
  float acc[16];
  #pragma unroll
  for (int c = 0; c < 16; ++c) acc[c] = 0.f;
  for (int kt = 0; kt < 2; ++kt) {
    __syncthreads();
    #pragma unroll
    for (int i = 0; i < 8; ++i) {
      int idx = t + 256 * i;
      int row = idx >> 5, kq = idx & 31;
      float4 v = *(const float4*)&xmn[(size_t)(row0 + row) * 256 + kt * 128 + kq * 4];
      *(float4*)&sa[row * 132 + kq * 4] = v;
    }
    __syncthreads();
    for (int k4 = 0; k4 < 32; ++k4) {
      float4 a4 = *(const float4*)&sa[l * 132 + k4 * 4];
      const float* wp = pw + (size_t)ob * 256 + kt * 128 + k4 * 4;
      #pragma unroll
      for (int c = 0; c < 16; ++c) {
        float4 w4 = *(const float4*)&wp[(size_t)c * 256];
        acc[c] += a4.x * w4.x + a4.y * w4.y + a4.z * w4.z + a4.w * w4.w;
      }
    }
  }
  // out is [b][o][l]: lanes along l -> coalesced direct stores
  #pragma unroll
  for (int c = 0; c < 16; ++c) {
    int o = ob + c;
    out[((size_t)b * OUT_ + o) * L_ + l0 + l] = acc[c] + pb[o];
  }
}

extern "C" void kernel_launch(void* const* d_in, const int* in_sizes, int n_in,
                              void* d_out, int out_size, void* d_ws, size_t ws_size,
                              hipStream_t stream) {
  (void)in_sizes; (void)n_in; (void)out_size; (void)ws_size;
  const float* x          = (const float*)d_in[0];
  const float* ln_g       = (const float*)d_in[1];
  const float* ln_b       = (const float*)d_in[2];
  const float* in_proj_w  = (const float*)d_in[3];
  const float* conv_w     = (const float*)d_in[4];
  const float* conv_b     = (const float*)d_in[5];
  const float* x_proj_w   = (const float*)d_in[6];
  const float* dt_proj_w  = (const float*)d_in[7];
  const float* dt_proj_b  = (const float*)d_in[8];
  const float* A_log      = (const float*)d_in[9];
  const float* D_param    = (const float*)d_in[10];
  const float* out_proj_w = (const float*)d_in[11];
  const float* proj_w     = (const float*)d_in[12];
  const float* proj_b     = (const float*)d_in[13];
  const float* skip_scale = (const float*)d_in[14];

  float* ws  = (float*)d_ws;
  float* xn  = ws;              // 2,097,152 f
  float* xz  = xn + 2097152;    // 8,388,608 f
  float* xc  = xz + 8388608;    // 4,194,304 f
  float* dt  = xc + 4194304;    // 4,194,304 f
  float* bc  = dt + 4194304;    // 1,048,576 f
  float* chA = bc + 1048576;    // 2,097,152 f
  float* chH = chA + 2097152;   // 2,097,152 f  (k4b3 writes exclusive prefixes)
  float* yg  = chH + 2097152;   // 4,194,304 f
  float* xmn = yg + 4194304;    // 2,097,152 f
  // k4b scratch reuses the (then-dead) xmn region: 3 x 262144 floats
  float* pA  = xmn;
  float* pH  = xmn + 262144;
  float* gH  = xmn + 524288;
  float* out = (float*)d_out;

  k1_ln<<<dim3(L_ / 32, B_), 256, 0, stream>>>(x, ln_g, ln_b, xn);
  k2_inproj<<<dim3(512, 4), 256, 0, stream>>>(xn, in_proj_w, xz);
  k3a_conv<<<dim3(128, B_ * P_), 256, 0, stream>>>(xz, conv_w, conv_b, xc);
  k3b_xdbl<<<dim3(512), 256, 0, stream>>>(xc, x_proj_w, dt_proj_w,
      dt_proj_b, bc, dt);
  k4a_scanA<<<dim3(NCH, B_ * P_), 128, 0, stream>>>(dt, xc, bc, A_log, chA, chH);
  k4b1<<<dim3(1024), 256, 0, stream>>>(chA, chH, pA, pH);
  k4b2<<<dim3(64), 256, 0, stream>>>(pA, pH, gH);
  k4b3<<<dim3(1024), 256, 0, stream>>>(chA, chH, gH);
  k5_scanB<<<dim3(NCH, B_ * P_), 128, 0, stream>>>(dt, xc, bc, xz, A_log,
      D_param, chH, yg);
  k6a_gemm<<<dim3(512), 256, 0, stream>>>(yg, xn, out_proj_w, skip_scale, xmn);
  k6ln<<<dim3(B_ * L_ / 4), 256, 0, stream>>>(xmn, ln_g, ln_b);
  k6b_proj<<<dim3(128, 4), 256, 0, stream>>>(xmn, proj_w, proj_b, out);
}

// Round 6
// 244.199 us; speedup vs baseline: 1.9104x; 1.0418x over previous
//
#include <hip/hip_runtime.h>

// PetaloMixer: LN -> 4x shared-weight Mamba over parts -> skip -> LN -> proj
// B=2, C=256, L=4096, P=4, DM=64, DI=128, DS=16, DTR=4, OUT=256. fp32.
// Wave-GEMM: block = 64 rows x 32 outs (4 waves x 8 outs). Wave-uniform o-set
// -> weights via s_load (SGPR FMA operand, zero operand BW); lane owns a row;
// A-tile in LDS, XOR-swizzled quads, 1 ds_read_b128 per 32 FMA -> VALU-bound.
// Scan: chunked, NCH=128 chunks of CHL=32, thread-owns-d; 3-level chunk fold.

#define B_    2
#define C_    256
#define L_    4096
#define P_    4
#define DM_   64
#define DI_   128
#define OUT_  256
#define NCH   128
#define CHL   32

// ---------------- K1: LayerNorm over C for (b,l), x is (b,c,l) ----------------
__global__ __launch_bounds__(256) void k1_ln(const float* __restrict__ x,
        const float* __restrict__ g, const float* __restrict__ bb,
        float* __restrict__ xn) {
  __shared__ float tile[256][33];
  __shared__ float psum[8][32];
  __shared__ float psq[8][32];
  __shared__ float smu[32], srs[32];
  int t = threadIdx.x;
  int l0 = blockIdx.x * 32;
  int b = blockIdx.y;
  const float* xb = x + (size_t)b * C_ * L_;
  int ll = t & 31, cr = t >> 5;
  for (int i = 0; i < 32; ++i) {
    int c = cr + 8 * i;
    tile[c][ll] = xb[(size_t)c * L_ + l0 + ll];
  }
  __syncthreads();
  {
    int l = t & 31, k = t >> 5;
    float s = 0.f, sq = 0.f;
    #pragma unroll 8
    for (int j = 0; j < 32; ++j) {
      float v = tile[32 * k + j][l];
      s += v; sq += v * v;
    }
    psum[k][l] = s; psq[k][l] = sq;
  }
  __syncthreads();
  if (t < 32) {
    float s = 0.f, sq = 0.f;
    #pragma unroll
    for (int k = 0; k < 8; ++k) { s += psum[k][t]; sq += psq[k][t]; }
    float mu = s * (1.f / 256.f);
    float var = sq * (1.f / 256.f) - mu * mu;
    smu[t] = mu;
    srs[t] = rsqrtf(var + 1e-5f);
  }
  __syncthreads();
  float gc = g[t], bc = bb[t];
  for (int l = 0; l < 32; ++l) {
    float v = (tile[t][l] - smu[l]) * srs[l] * gc + bc;
    xn[((size_t)b * L_ + l0 + l) * C_ + t] = v;
  }
}

// ---------------- K2 v4: xz[row, o0:o0+32] = xn_part[row,64] @ W^T -----------
// grid (512, 8), 256 thr. K=64 single stage.
__global__ __launch_bounds__(256) void k2_inproj(const float* __restrict__ xn,
        const float* __restrict__ w, float* __restrict__ xz) {
  __shared__ float sa[64 * 64];
  int t = threadIdx.x;
  int row0 = blockIdx.x * 64;
  int o0 = blockIdx.y * 32;
  int bp = row0 >> 12, b = bp >> 2, p = bp & 3, l0 = row0 & 4095;
  // stage A: 64 rows x 16 quads, XOR-swizzled
  #pragma unroll
  for (int i = 0; i < 4; ++i) {
    int idx = t + 256 * i;
    int row = idx >> 4, kq = idx & 15;
    float4 v = *(const float4*)&xn[((size_t)b * L_ + l0 + row) * 256 + p * 64 + kq * 4];
    *(float4*)&sa[row * 64 + ((kq ^ (row & 15)) << 2)] = v;
  }
  __syncthreads();
  int lane = t & 63;
  int wid = __builtin_amdgcn_readfirstlane(t >> 6);
  int ob = o0 + wid * 8;
  const float* wp0 = w + (size_t)ob * 64;
  float acc[8];
  #pragma unroll
  for (int c = 0; c < 8; ++c) acc[c] = 0.f;
  #pragma unroll 2
  for (int k4 = 0; k4 < 16; ++k4) {
    float4 a4 = *(const float4*)&sa[lane * 64 + ((k4 ^ (lane & 15)) << 2)];
    #pragma unroll
    for (int c = 0; c < 8; ++c) {
      float4 w4 = *(const float4*)&wp0[c * 64 + k4 * 4];
      acc[c] += a4.x * w4.x + a4.y * w4.y + a4.z * w4.z + a4.w * w4.w;
    }
  }
  // transpose through LDS (reuse sa) for coalesced stores
  __syncthreads();
  int widl = t >> 6;
  #pragma unroll
  for (int c = 0; c < 8; ++c) sa[lane * 33 + widl * 8 + c] = acc[c];
  __syncthreads();
  {
    int row = t >> 2, c0 = (t & 3) * 8;
    float4 v0 = *(const float4*)&sa[row * 33 + c0];
    float4 v1 = *(const float4*)&sa[row * 33 + c0 + 4];
    float* op = &xz[(size_t)(row0 + row) * 256 + o0 + c0];
    *(float4*)op = v0;
    *(float4*)&op[4] = v1;
  }
}

// ---------------- K3a: causal depthwise conv(4) + silu (streaming) -----------
__global__ __launch_bounds__(256) void k3a_conv(const float* __restrict__ xz,
        const float* __restrict__ conv_w, const float* __restrict__ conv_b,
        float* __restrict__ xc) {
  int t = threadIdx.x;
  int d = t & 127, lh = t >> 7;
  int bp = blockIdx.y;
  int lstart = blockIdx.x * 32 + lh * 16;
  const float* xzb = xz + (size_t)bp * L_ * 256;
  float4 cw = *(const float4*)&conv_w[d * 4];
  float cb = conv_b[d];
  float w0 = (lstart >= 3) ? xzb[(size_t)(lstart - 3) * 256 + d] : 0.f;
  float w1 = (lstart >= 2) ? xzb[(size_t)(lstart - 2) * 256 + d] : 0.f;
  float w2 = (lstart >= 1) ? xzb[(size_t)(lstart - 1) * 256 + d] : 0.f;
  const float* xzrow = xzb + (size_t)lstart * 256 + d;
  float* xcrow = xc + ((size_t)bp * L_ + lstart) * 128 + d;
  #pragma unroll 4
  for (int i = 0; i < 16; ++i) {
    float w3 = xzrow[(size_t)i * 256];
    float cv = cb + cw.x * w0 + cw.y * w1 + cw.z * w2 + cw.w * w3;
    float sv = __fdividef(cv, 1.f + __expf(-cv));
    xcrow[(size_t)i * 128] = sv;
    w0 = w1; w1 = w2; w2 = w3;
  }
}

// ---------------- K3b v4: x_dbl = xc @ x_proj_w^T, fused dt ------------------
// grid (512), 256 thr = 4 waves x 9 outs. K=128 in 2 stages of 64.
__global__ __launch_bounds__(256) void k3b_xdbl(const float* __restrict__ xc,
        const float* __restrict__ x_proj_w, const float* __restrict__ dt_proj_w,
        const float* __restrict__ dt_proj_b,
        float* __restrict__ bc, float* __restrict__ dt) {
  __shared__ float sa[64 * 64];
  __shared__ float sbc[64 * 33];
  __shared__ float sdb[64 * 8];
  int t = threadIdx.x;
  int row0 = blockIdx.x * 64;
  int lane = t & 63;
  int wid = __builtin_amdgcn_readfirstlane(t >> 6);
  const float* wbase = x_proj_w + (size_t)(wid * 9) * 128;
  float acc[9];
  #pragma unroll
  for (int rr = 0; rr < 9; ++rr) acc[rr] = 0.f;
  for (int kt = 0; kt < 2; ++kt) {
    if (kt) __syncthreads();
    #pragma unroll
    for (int i = 0; i < 4; ++i) {
      int idx = t + 256 * i;
      int row = idx >> 4, kq = idx & 15;
      float4 v = *(const float4*)&xc[(size_t)(row0 + row) * 128 + kt * 64 + kq * 4];
      *(float4*)&sa[row * 64 + ((kq ^ (row & 15)) << 2)] = v;
    }
    __syncthreads();
    #pragma unroll 2
    for (int k4 = 0; k4 < 16; ++k4) {
      float4 a4 = *(const float4*)&sa[lane * 64 + ((k4 ^ (lane & 15)) << 2)];
      #pragma unroll
      for (int rr = 0; rr < 9; ++rr) {
        float4 w4 = *(const float4*)&wbase[rr * 128 + kt * 64 + k4 * 4];
        acc[rr] += a4.x * w4.x + a4.y * w4.y + a4.z * w4.z + a4.w * w4.w;
      }
    }
  }
  if (wid == 0) {
    #pragma unroll
    for (int rr = 0; rr < 4; ++rr) sdb[lane * 8 + rr] = acc[rr];
    #pragma unroll
    for (int rr = 4; rr < 9; ++rr) sbc[lane * 33 + (rr - 4)] = acc[rr];
  } else {
    #pragma unroll
    for (int rr = 0; rr < 9; ++rr) sbc[lane * 33 + (wid * 9 + rr - 4)] = acc[rr];
  }
  __syncthreads();
  // coalesced bc writeout
  #pragma unroll
  for (int i = 0; i < 8; ++i) {
    int idx = t + 256 * i;
    int row = idx >> 5, col = idx & 31;
    bc[(size_t)(row0 + row) * 32 + col] = sbc[row * 33 + col];
  }
  // dt = softplus(partials @ dt_proj_w^T + b)
  {
    int d = t & 127, rh = t >> 7;
    float4 dw = *(const float4*)&dt_proj_w[d * 4];
    float dpb = dt_proj_b[d];
    #pragma unroll 4
    for (int i = 0; i < 32; ++i) {
      int row = rh * 32 + i;
      float4 q = *(const float4*)&sdb[row * 8];
      float v = dpb + q.x * dw.x + q.y * dw.y + q.z * dw.z + q.w * dw.w;
      float sp = (v > 20.f) ? v : __logf(1.f + __expf(v));
      dt[(size_t)(row0 + row) * 128 + d] = sp;
    }
  }
}

// ---------------- K4a: per-chunk (aprod, h_end | h0=0), thread owns d --------
__global__ __launch_bounds__(128) void k4a_scanA(const float* __restrict__ dt,
        const float* __restrict__ xc, const float* __restrict__ bcbuf,
        const float* __restrict__ A_log,
        float* __restrict__ chA, float* __restrict__ chH) {
  int d = threadIdx.x;
  int ch = blockIdx.x, bp = blockIdx.y;
  float Av[16], h[16];
  #pragma unroll
  for (int q = 0; q < 4; ++q) {
    float4 a = *(const float4*)&A_log[d * 16 + q * 4];
    Av[q*4+0] = -__expf(a.x); Av[q*4+1] = -__expf(a.y);
    Av[q*4+2] = -__expf(a.z); Av[q*4+3] = -__expf(a.w);
  }
  #pragma unroll
  for (int s = 0; s < 16; ++s) h[s] = 0.f;
  float sumdt = 0.f;
  const float* dtp = dt + (size_t)bp * L_ * 128 + (size_t)ch * CHL * 128 + d;
  const float* xcp = xc + (size_t)bp * L_ * 128 + (size_t)ch * CHL * 128 + d;
  const float* bcp = bcbuf + (size_t)bp * L_ * 32 + (size_t)ch * CHL * 32;
  #pragma unroll 2
  for (int tt = 0; tt < CHL; ++tt) {
    float dtv = dtp[tt * 128];
    float xcv = xcp[tt * 128];
    float Bv[16];
    *(float4*)&Bv[0]  = *(const float4*)&bcp[tt * 32 + 0];
    *(float4*)&Bv[4]  = *(const float4*)&bcp[tt * 32 + 4];
    *(float4*)&Bv[8]  = *(const float4*)&bcp[tt * 32 + 8];
    *(float4*)&Bv[12] = *(const float4*)&bcp[tt * 32 + 12];
    float w = dtv * xcv;
    sumdt += dtv;
    #pragma unroll
    for (int s = 0; s < 16; ++s) {
      float dA = __expf(dtv * Av[s]);
      h[s] = fmaf(dA, h[s], w * Bv[s]);
    }
  }
  size_t o = (((size_t)bp * NCH + ch) * 128 + d) * 16;
  #pragma unroll
  for (int s = 0; s < 16; ++s) chA[o + s] = __expf(sumdt * Av[s]);
  #pragma unroll
  for (int s = 0; s < 16; ++s) chH[o + s] = h[s];
}

// ---------------- K4b: 3-level chunk-state fold (chain 128 -> 8/16/8) --------
__global__ __launch_bounds__(256) void k4b1(const float* __restrict__ chA,
        const float* __restrict__ chH, float* __restrict__ pA,
        float* __restrict__ pH) {
  int tid = blockIdx.x * 256 + threadIdx.x;   // 262144
  int rem = tid & 2047, g = (tid >> 11) & 15, bp = tid >> 15;
  float a = 1.f, h = 0.f;
  #pragma unroll 2
  for (int i = 0; i < 8; ++i) {
    size_t o = ((size_t)(bp * NCH + g * 8 + i)) * 2048 + rem;
    float ca = chA[o], ce = chH[o];
    h = fmaf(ca, h, ce);
    a *= ca;
  }
  pA[tid] = a; pH[tid] = h;
}

__global__ __launch_bounds__(256) void k4b2(const float* __restrict__ pA,
        const float* __restrict__ pH, float* __restrict__ gH) {
  int tid = blockIdx.x * 256 + threadIdx.x;   // 16384
  int rem = tid & 2047, bp = tid >> 11;
  float h = 0.f;
  for (int g = 0; g < 16; ++g) {
    int o = (bp << 15) + (g << 11) + rem;
    gH[o] = h;
    h = fmaf(pA[o], h, pH[o]);
  }
}

__global__ __launch_bounds__(256) void k4b3(const float* __restrict__ chA,
        float* __restrict__ chH, const float* __restrict__ gH) {
  int tid = blockIdx.x * 256 + threadIdx.x;   // 262144
  int rem = tid & 2047, g = (tid >> 11) & 15, bp = tid >> 15;
  float h = gH[tid];
  #pragma unroll 2
  for (int i = 0; i < 8; ++i) {
    size_t o = ((size_t)(bp * NCH + g * 8 + i)) * 2048 + rem;
    float a = chA[o], e = chH[o];
    chH[o] = h;           // exclusive prefix for k5
    h = fmaf(a, h, e);
  }
}

// ---------------- K5: outputs — recurrence from h0, y, D-skip, silu(z) gate --
__global__ __launch_bounds__(128) void k5_scanB(const float* __restrict__ dt,
        const float* __restrict__ xc, const float* __restrict__ bcbuf,
        const float* __restrict__ xz, const float* __restrict__ A_log,
        const float* __restrict__ D_param, const float* __restrict__ chH,
        float* __restrict__ yg) {
  int d = threadIdx.x;
  int ch = blockIdx.x, bp = blockIdx.y;
  float Av[16], h[16];
  #pragma unroll
  for (int q = 0; q < 4; ++q) {
    float4 a = *(const float4*)&A_log[d * 16 + q * 4];
    Av[q*4+0] = -__expf(a.x); Av[q*4+1] = -__expf(a.y);
    Av[q*4+2] = -__expf(a.z); Av[q*4+3] = -__expf(a.w);
  }
  {
    size_t o = (((size_t)bp * NCH + ch) * 128 + d) * 16;
    #pragma unroll
    for (int q = 0; q < 4; ++q)
      *(float4*)&h[q * 4] = *(const float4*)&chH[o + q * 4];
  }
  float Dv = D_param[d];
  const float* dtp = dt + (size_t)bp * L_ * 128 + (size_t)ch * CHL * 128 + d;
  const float* xcp = xc + (size_t)bp * L_ * 128 + (size_t)ch * CHL * 128 + d;
  const float* bcp = bcbuf + (size_t)bp * L_ * 32 + (size_t)ch * CHL * 32;
  const float* zp  = xz + (size_t)bp * L_ * 256 + (size_t)ch * CHL * 256 + 128 + d;
  float* ygp = yg + (size_t)bp * L_ * 128 + (size_t)ch * CHL * 128 + d;
  #pragma unroll 2
  for (int tt = 0; tt < CHL; ++tt) {
    float dtv = dtp[tt * 128];
    float xcv = xcp[tt * 128];
    float zv  = zp[tt * 256];
    float Bv[16], Cv[16];
    *(float4*)&Bv[0]  = *(const float4*)&bcp[tt * 32 + 0];
    *(float4*)&Bv[4]  = *(const float4*)&bcp[tt * 32 + 4];
    *(float4*)&Bv[8]  = *(const float4*)&bcp[tt * 32 + 8];
    *(float4*)&Bv[12] = *(const float4*)&bcp[tt * 32 + 12];
    *(float4*)&Cv[0]  = *(const float4*)&bcp[tt * 32 + 16];
    *(float4*)&Cv[4]  = *(const float4*)&bcp[tt * 32 + 20];
    *(float4*)&Cv[8]  = *(const float4*)&bcp[tt * 32 + 24];
    *(float4*)&Cv[12] = *(const float4*)&bcp[tt * 32 + 28];
    float w = dtv * xcv;
    float r = 0.f;
    #pragma unroll
    for (int s = 0; s < 16; ++s) {
      float dA = __expf(dtv * Av[s]);
      h[s] = fmaf(dA, h[s], w * Bv[s]);
      r = fmaf(h[s], Cv[s], r);
    }
    float y = fmaf(Dv, xcv, r);
    float sig = __fdividef(1.f, 1.f + __expf(-zv));
    ygp[tt * 128] = y * (zv * sig);
  }
}

// ---------------- K6a v4: out_proj + skip ------------------------------------
// grid (512, 2), 256 thr = 4 waves x 8 outs. K=128 in 2 stages of 64.
__global__ __launch_bounds__(256) void k6a_gemm(const float* __restrict__ yg,
        const float* __restrict__ xn, const float* __restrict__ opw,
        const float* __restrict__ skip, float* __restrict__ xmn) {
  __shared__ float sa[64 * 64];
  int t = threadIdx.x;
  int row0 = blockIdx.x * 64;
  int o0 = blockIdx.y * 32;
  int bp = row0 >> 12, b = bp >> 2, p = bp & 3, l0 = row0 & 4095;
  int lane = t & 63;
  int wid = __builtin_amdgcn_readfirstlane(t >> 6);
  int ob = o0 + wid * 8;
  const float* wp0 = opw + (size_t)ob * 128;
  float acc[8];
  #pragma unroll
  for (int c = 0; c < 8; ++c) acc[c] = 0.f;
  for (int kt = 0; kt < 2; ++kt) {
    if (kt) __syncthreads();
    #pragma unroll
    for (int i = 0; i < 4; ++i) {
      int idx = t + 256 * i;
      int row = idx >> 4, kq = idx & 15;
      float4 v = *(const float4*)&yg[(size_t)(row0 + row) * 128 + kt * 64 + kq * 4];
      *(float4*)&sa[row * 64 + ((kq ^ (row & 15)) << 2)] = v;
    }
    __syncthreads();
    #pragma unroll 2
    for (int k4 = 0; k4 < 16; ++k4) {
      float4 a4 = *(const float4*)&sa[lane * 64 + ((k4 ^ (lane & 15)) << 2)];
      #pragma unroll
      for (int c = 0; c < 8; ++c) {
        float4 w4 = *(const float4*)&wp0[c * 128 + kt * 64 + k4 * 4];
        acc[c] += a4.x * w4.x + a4.y * w4.y + a4.z * w4.z + a4.w * w4.w;
      }
    }
  }
  // transpose through LDS (reuse sa) + fused skip-add
  __syncthreads();
  int widl = t >> 6;
  #pragma unroll
  for (int c = 0; c < 8; ++c) sa[lane * 33 + widl * 8 + c] = acc[c];
  __syncthreads();
  {
    float sk = skip[0];
    int row = t >> 2, c0 = (t & 3) * 8;
    size_t addr = ((size_t)b * L_ + l0 + row) * 256 + p * 64 + o0 + c0;
    float4 v0 = *(const float4*)&sa[row * 33 + c0];
    float4 v1 = *(const float4*)&sa[row * 33 + c0 + 4];
    float4 x0 = *(const float4*)&xn[addr];
    float4 x1 = *(const float4*)&xn[addr + 4];
    float4 o0v = make_float4(v0.x + sk * x0.x, v0.y + sk * x0.y,
                             v0.z + sk * x0.z, v0.w + sk * x0.w);
    float4 o1v = make_float4(v1.x + sk * x1.x, v1.y + sk * x1.y,
                             v1.z + sk * x1.z, v1.w + sk * x1.w);
    *(float4*)&xmn[addr] = o0v;
    *(float4*)&xmn[addr + 4] = o1v;
  }
}

// ---------------- K6ln: row LayerNorm over C (rows contiguous), in-place -----
__global__ __launch_bounds__(256) void k6ln(float* __restrict__ xmn,
        const float* __restrict__ g, const float* __restrict__ bb) {
  int t = threadIdx.x;
  int row = blockIdx.x * 4 + (t >> 6);
  int lane = t & 63;
  float* rp = xmn + (size_t)row * 256 + lane * 4;
  float4 v = *(const float4*)rp;
  float s = v.x + v.y + v.z + v.w;
  float q = v.x * v.x + v.y * v.y + v.z * v.z + v.w * v.w;
  #pragma unroll
  for (int off = 1; off < 64; off <<= 1) {
    s += __shfl_xor(s, off);
    q += __shfl_xor(q, off);
  }
  float mu = s * (1.f / 256.f);
  float rs = rsqrtf(q * (1.f / 256.f) - mu * mu + 1e-5f);
  float4 g4 = *(const float4*)&g[lane * 4];
  float4 b4 = *(const float4*)&bb[lane * 4];
  float4 o = make_float4((v.x - mu) * rs * g4.x + b4.x,
                         (v.y - mu) * rs * g4.y + b4.y,
                         (v.z - mu) * rs * g4.z + b4.z,
                         (v.w - mu) * rs * g4.w + b4.w);
  *(float4*)rp = o;
}

// ---------------- K6b v4: out[b,o,l] = xmn[row,:] @ proj_w[o,:] + pb[o] ------
// grid (128, 8), 256 thr = 4 waves x 8 outs. K=256 in 4 stages of 64.
// Output stores are lane-contiguous along l: directly coalesced.
__global__ __launch_bounds__(256) void k6b_proj(const float* __restrict__ xmn,
        const float* __restrict__ pw, const float* __restrict__ pb,
        float* __restrict__ out) {
  __shared__ float sa[64 * 64];
  int t = threadIdx.x;
  int row0 = blockIdx.x * 64;
  int o0 = blockIdx.y * 32;
  int b = row0 >> 12, l0 = row0 & 4095;
  int lane = t & 63;
  int wid = __builtin_amdgcn_readfirstlane(t >> 6);
  int ob = o0 + wid * 8;
  const float* wp0 = pw + (size_t)ob * 256;
  float acc[8];
  #pragma unroll
  for (int c = 0; c < 8; ++c) acc[c] = 0.f;
  for (int kt = 0; kt < 4; ++kt) {
    if (kt) __syncthreads();
    #pragma unroll
    for (int i = 0; i < 4; ++i) {
      int idx = t + 256 * i;
      int row = idx >> 4, kq = idx & 15;
      float4 v = *(const float4*)&xmn[(size_t)(row0 + row) * 256 + kt * 64 + kq * 4];
      *(float4*)&sa[row * 64 + ((kq ^ (row & 15)) << 2)] = v;
    }
    __syncthreads();
    #pragma unroll 2
    for (int k4 = 0; k4 < 16; ++k4) {
      float4 a4 = *(const float4*)&sa[lane * 64 + ((k4 ^ (lane & 15)) << 2)];
      #pragma unroll
      for (int c = 0; c < 8; ++c) {
        float4 w4 = *(const float4*)&wp0[c * 256 + kt * 64 + k4 * 4];
        acc[c] += a4.x * w4.x + a4.y * w4.y + a4.z * w4.z + a4.w * w4.w;
      }
    }
  }
  #pragma unroll
  for (int c = 0; c < 8; ++c) {
    int o = ob + c;
    out[((size_t)b * OUT_ + o) * L_ + l0 + lane] = acc[c] + pb[o];
  }
}

extern "C" void kernel_launch(void* const* d_in, const int* in_sizes, int n_in,
                              void* d_out, int out_size, void* d_ws, size_t ws_size,
                              hipStream_t stream) {
  (void)in_sizes; (void)n_in; (void)out_size; (void)ws_size;
  const float* x          = (const float*)d_in[0];
  const float* ln_g       = (const float*)d_in[1];
  const float* ln_b       = (const float*)d_in[2];
  const float* in_proj_w  = (const float*)d_in[3];
  const float* conv_w     = (const float*)d_in[4];
  const float* conv_b     = (const float*)d_in[5];
  const float* x_proj_w   = (const float*)d_in[6];
  const float* dt_proj_w  = (const float*)d_in[7];
  const float* dt_proj_b  = (const float*)d_in[8];
  const float* A_log      = (const float*)d_in[9];
  const float* D_param    = (const float*)d_in[10];
  const float* out_proj_w = (const float*)d_in[11];
  const float* proj_w     = (const float*)d_in[12];
  const float* proj_b     = (const float*)d_in[13];
  const float* skip_scale = (const float*)d_in[14];

  float* ws  = (float*)d_ws;
  float* xn  = ws;              // 2,097,152 f
  float* xz  = xn + 2097152;    // 8,388,608 f
  float* xc  = xz + 8388608;    // 4,194,304 f
  float* dt  = xc + 4194304;    // 4,194,304 f
  float* bc  = dt + 4194304;    // 1,048,576 f
  float* chA = bc + 1048576;    // 2,097,152 f
  float* chH = chA + 2097152;   // 2,097,152 f  (k4b3 writes exclusive prefixes)
  float* yg  = chH + 2097152;   // 4,194,304 f
  float* xmn = yg + 4194304;    // 2,097,152 f
  // k4b scratch reuses the (then-dead) xmn region: 3 x 262144 floats
  float* pA  = xmn;
  float* pH  = xmn + 262144;
  float* gH  = xmn + 524288;
  float* out = (float*)d_out;

  k1_ln<<<dim3(L_ / 32, B_), 256, 0, stream>>>(x, ln_g, ln_b, xn);
  k2_inproj<<<dim3(512, 8), 256, 0, stream>>>(xn, in_proj_w, xz);
  k3a_conv<<<dim3(128, B_ * P_), 256, 0, stream>>>(xz, conv_w, conv_b, xc);
  k3b_xdbl<<<dim3(512), 256, 0, stream>>>(xc, x_proj_w, dt_proj_w,
      dt_proj_b, bc, dt);
  k4a_scanA<<<dim3(NCH, B_ * P_), 128, 0, stream>>>(dt, xc, bc, A_log, chA, chH);
  k4b1<<<dim3(1024), 256, 0, stream>>>(chA, chH, pA, pH);
  k4b2<<<dim3(64), 256, 0, stream>>>(pA, pH, gH);
  k4b3<<<dim3(1024), 256, 0, stream>>>(chA, chH, gH);
  k5_scanB<<<dim3(NCH, B_ * P_), 128, 0, stream>>>(dt, xc, bc, xz, A_log,
      D_param, chH, yg);
  k6a_gemm<<<dim3(512, 2), 256, 0, stream>>>(yg, xn, out_proj_w, skip_scale, xmn);
  k6ln<<<dim3(B_ * L_ / 4), 256, 0, stream>>>(xmn, ln_g, ln_b);
  k6b_proj<<<dim3(128, 8), 256, 0, stream>>>(xmn, proj_w, proj_b, out);
}